// Round 1
// baseline (867.027 us; speedup 1.0000x reference)
//
#include <hip/hip_runtime.h>
#include <stdint.h>

#define BS 16
#define NP 25200
#define NC 80
#define DIM 85
#define KN 2048
#define CAP 4096
#define BINS 512
#define MAXD 300
#define NBLK 394   // ceil(25200/64)

// ---------------------------------------------------------------- score
// One block = 64 boxes staged through LDS (coalesced). 4 lanes per box
// compute max/argmax of cls*obj with jnp.argmax first-index tie semantics.
__global__ __launch_bounds__(256) void score_kernel(const float* __restrict__ preds,
        float* __restrict__ score, int* __restrict__ clsout, int* __restrict__ hist) {
    int b = blockIdx.x / NBLK;
    int blk = blockIdx.x % NBLK;
    int i0 = blk * 64;
    int nb = min(64, NP - i0);
    __shared__ float s[64 * DIM];
    const float* p = preds + ((size_t)b * NP + i0) * DIM;
    int tot = nb * DIM;
    for (int t = threadIdx.x; t < tot; t += 256) s[t] = p[t];
    __syncthreads();
    int box = threadIdx.x >> 2, sub = threadIdx.x & 3;
    if (box < nb) {
        const float* bp = s + box * DIM;
        float obj = bp[4];
        float best = -1.0f; int bidx = sub * 20;
        #pragma unroll
        for (int c = 0; c < 20; ++c) {
            float v = bp[5 + sub * 20 + c] * obj;
            if (v > best) { best = v; bidx = sub * 20 + c; }   // strict > keeps first index
        }
        #pragma unroll
        for (int off = 1; off < 4; off <<= 1) {
            float ob = __shfl_xor(best, off);
            int   oi = __shfl_xor(bidx, off);
            if (ob > best || (ob == best && oi < bidx)) { best = ob; bidx = oi; }
        }
        if (sub == 0) {
            bool m = (obj > 0.25f) && (best > 0.25f);
            float sc = m ? best : -1.0f;
            int gi = b * NP + i0 + box;
            score[gi] = sc;
            clsout[gi] = bidx;
            if (sc > 0.0f) {
                int bin = (int)(__float_as_uint(sc) >> 16) - 0x3E80;
                bin = max(0, min(BINS - 1, bin));
                atomicAdd(&hist[b * BINS + bin], 1);
            }
        }
    }
}

// ---------------------------------------------------------------- threshold
__global__ __launch_bounds__(64) void thresh_kernel(const int* __restrict__ hist,
        int* __restrict__ T) {
    int b = blockIdx.x;
    __shared__ int h[BINS];
    for (int t = threadIdx.x; t < BINS; t += 64) h[t] = hist[b * BINS + t];
    __syncthreads();
    if (threadIdx.x == 0) {
        int c = 0, tb = 0;
        for (int bin = BINS - 1; bin >= 0; --bin) {
            c += h[bin];
            if (c >= KN) { tb = bin; break; }
        }
        T[b] = tb;   // gather everything in bins >= tb (>= 2048 elems, or all if fewer)
    }
}

// ---------------------------------------------------------------- gather
__global__ __launch_bounds__(256) void gather_kernel(const float* __restrict__ score,
        const int* __restrict__ T, int* __restrict__ cnt,
        unsigned long long* __restrict__ keys) {
    int idx = blockIdx.x * 256 + threadIdx.x;
    if (idx >= BS * NP) return;
    int b = idx / NP;
    float sc = score[idx];
    if (sc > 0.0f) {
        int bin = (int)(__float_as_uint(sc) >> 16) - 0x3E80;
        bin = max(0, min(BINS - 1, bin));
        if (bin >= T[b]) {
            int pos = atomicAdd(&cnt[b], 1);
            if (pos < CAP) {
                unsigned int i = (unsigned int)(idx - b * NP);
                // desc sort => value desc, index asc (jax.lax.top_k tie rule)
                keys[(size_t)b * CAP + pos] =
                    ((unsigned long long)__float_as_uint(sc) << 32) | (unsigned int)(~i);
            }
        }
    }
}

// ---------------------------------------------------------------- sort + build candidates
__global__ __launch_bounds__(512) void sort_build_kernel(const unsigned long long* __restrict__ keys,
        const int* __restrict__ cnt, const float* __restrict__ preds, const int* __restrict__ cls,
        float4* __restrict__ boxes, float4* __restrict__ boff,
        float* __restrict__ cscore, int* __restrict__ ccls, int* __restrict__ M) {
    int b = blockIdx.x;
    __shared__ unsigned long long k[CAP];
    int n = min(cnt[b], CAP);
    for (int t = threadIdx.x; t < CAP; t += 512)
        k[t] = (t < n) ? keys[(size_t)b * CAP + t] : 0ull;   // 0 pads sort last
    __syncthreads();
    for (int size = 2; size <= CAP; size <<= 1) {
        for (int stride = size >> 1; stride > 0; stride >>= 1) {
            for (int t = threadIdx.x; t < CAP / 2; t += 512) {
                int i = 2 * t - (t & (stride - 1));
                int j = i + stride;
                bool asc = (t & (size >> 1)) != 0;
                unsigned long long a = k[i], bb = k[j];
                bool sw = asc ? (a > bb) : (a < bb);
                if (sw) { k[i] = bb; k[j] = a; }
            }
            __syncthreads();
        }
    }
    int Mb = min(n, KN);
    for (int r = threadIdx.x; r < KN; r += 512) {
        float4 bx = make_float4(0.f, 0.f, 0.f, 0.f);
        float4 bo = make_float4(0.f, 0.f, 0.f, 0.f);
        float sc = 0.0f; int c = 0;
        if (r < Mb) {
            unsigned long long key = k[r];
            unsigned int i = ~(unsigned int)key;
            sc = __uint_as_float((unsigned int)(key >> 32));
            const float* p = preds + ((size_t)b * NP + i) * DIM;
            float x = p[0], y = p[1], w = p[2], h = p[3];
            float x1 = x - w * 0.5f, y1 = y - h * 0.5f;
            float x2 = x + w * 0.5f, y2 = y + h * 0.5f;
            c = cls[(size_t)b * NP + i];
            float off = (float)c * 7680.0f;
            bx = make_float4(x1, y1, x2, y2);
            bo = make_float4(x1 + off, y1 + off, x2 + off, y2 + off);
        }
        boxes [b * KN + r] = bx;
        boff  [b * KN + r] = bo;
        cscore[b * KN + r] = sc;
        ccls  [b * KN + r] = c;
    }
    if (threadIdx.x == 0) M[b] = Mb;
}

// ---------------------------------------------------------------- suppression bitmask
// mask[b][i][w] : u32 word w covers cols j in [32w, 32w+32). bit = (iou>0.45 && j>i)
__global__ __launch_bounds__(256) void iou_kernel(const float4* __restrict__ boff,
        uint32_t* __restrict__ mask) {
    int b = blockIdx.x >> 5;
    int g = blockIdx.x & 31;           // 64-row group
    __shared__ float4 sb[KN];          // 32 KB
    __shared__ uint32_t mbuf[64 * 64]; // 16 KB
    const float4* Bb = boff + b * KN;
    for (int t = threadIdx.x; t < KN; t += 256) sb[t] = Bb[t];
    __syncthreads();
    int r = threadIdx.x >> 2;
    int w0 = threadIdx.x & 3;
    int i = g * 64 + r;
    float4 bi = sb[i];
    float ai = (bi.z - bi.x) * (bi.w - bi.y);
    #pragma unroll 1
    for (int kk = 0; kk < 16; ++kk) {
        int w = w0 + kk * 4;
        uint32_t bits = 0;
        if (32 * w + 31 > i) {
            #pragma unroll
            for (int jj = 0; jj < 32; ++jj) {
                int j = 32 * w + jj;
                if (j > i) {
                    float4 bj = sb[j];
                    float aj = (bj.z - bj.x) * (bj.w - bj.y);
                    float lx = fmaxf(bi.x, bj.x), ly = fmaxf(bi.y, bj.y);
                    float rx = fminf(bi.z, bj.z), ry = fminf(bi.w, bj.w);
                    float iw = fmaxf(rx - lx, 0.0f), ih = fmaxf(ry - ly, 0.0f);
                    float inter = iw * ih;
                    float iou = inter / (ai + aj - inter + 1e-7f);  // exact IEEE div, matches ref
                    if (iou > 0.45f) bits |= (1u << jj);
                }
            }
        }
        mbuf[r * 64 + w] = bits;
    }
    __syncthreads();
    size_t base = ((size_t)b * KN + (size_t)g * 64) * 64;
    for (int t = threadIdx.x; t < 4096; t += 256) mask[base + t] = mbuf[t];
}

// ---------------------------------------------------------------- sequential greedy scan
// One wave per batch. suppressed: 32 bits/lane (lane l owns cols [32l,32l+32)).
// 64-row chunks: chunk-local suppressed bits replicated in a u64 so the serial
// dependency is pure VALU; row masks double-buffered in registers.
__global__ __launch_bounds__(64) void scan_kernel(const uint32_t* __restrict__ mask,
        const int* __restrict__ M, uint32_t* __restrict__ keepw) {
    int b = blockIdx.x;
    int lane = threadIdx.x;
    const uint32_t* mb = mask + (size_t)b * KN * 64;
    int Mb = M[b];
    uint32_t sup = 0, keep = 0;
    uint32_t cur[64], nxt[64];
    #pragma unroll
    for (int r = 0; r < 64; ++r) cur[r] = mb[r * 64 + lane];
    for (int c = 0; c < 32; ++c) {
        if (c < 31) {
            #pragma unroll
            for (int r = 0; r < 64; ++r) nxt[r] = mb[(c + 1) * 4096 + r * 64 + lane];
        }
        unsigned long long cur64 =
            ((unsigned long long)(unsigned int)__shfl((int)sup, 2 * c + 1) << 32) |
            (unsigned int)__shfl((int)sup, 2 * c);
        #pragma unroll
        for (int r = 0; r < 64; ++r) {
            int i = c * 64 + r;
            uint32_t rw = cur[r];
            unsigned long long rb64 =
                ((unsigned long long)(unsigned int)__shfl((int)rw, 2 * c + 1) << 32) |
                (unsigned int)__shfl((int)rw, 2 * c);
            bool kp = (i < Mb) && !((cur64 >> r) & 1ull);
            unsigned long long km = kp ? ~0ull : 0ull;
            cur64 |= rb64 & km;
            sup |= rw & (uint32_t)km;
            if (lane == (i >> 5)) keep |= ((uint32_t)kp) << (i & 31);
        }
        if (c < 31) {
            #pragma unroll
            for (int r = 0; r < 64; ++r) cur[r] = nxt[r];
        }
    }
    keepw[b * 64 + lane] = keep;
}

// ---------------------------------------------------------------- output
__global__ __launch_bounds__(64) void output_kernel(const uint32_t* __restrict__ keepw,
        const float4* __restrict__ boxes, const float* __restrict__ cscore,
        const int* __restrict__ ccls, float* __restrict__ out) {
    int b = blockIdx.x;
    int lane = threadIdx.x;
    uint32_t kw = keepw[b * 64 + lane];
    int cnt = __popc(kw);
    int pre = cnt;
    for (int off = 1; off < 64; off <<= 1) {
        int v = __shfl_up(pre, off);
        if (lane >= off) pre += v;
    }
    pre -= cnt;   // exclusive prefix of kept rows before this lane's 32 rows
    uint32_t m = kw;
    while (m) {
        int bit = __ffs(m) - 1;
        m &= m - 1;
        int r = lane * 32 + bit;
        int p = pre++;
        if (p < MAXD) {
            float4 bx = boxes[b * KN + r];
            float* o = out + ((size_t)b * MAXD + p) * 6;
            o[0] = bx.x * 3.0f;      // 1920/640
            o[1] = bx.y * 1.6875f;   // 1080/640
            o[2] = bx.z * 3.0f;
            o[3] = bx.w * 1.6875f;
            o[4] = cscore[b * KN + r];
            o[5] = (float)ccls[b * KN + r];
        }
    }
}

// ---------------------------------------------------------------- launch
extern "C" void kernel_launch(void* const* d_in, const int* in_sizes, int n_in,
                              void* d_out, int out_size, void* d_ws, size_t ws_size,
                              hipStream_t stream) {
    const float* preds = (const float*)d_in[0];
    float* out = (float*)d_out;
    char* ws = (char*)d_ws;
    size_t off = 0;
    auto alloc = [&](size_t bytes) -> void* {
        void* p = ws + off;
        off += (bytes + 255) & ~(size_t)255;
        return p;
    };
    int* hist   = (int*)alloc((size_t)BS * BINS * 4);
    int* cnt    = (int*)alloc(BS * 4);
    float* score = (float*)alloc((size_t)BS * NP * 4);
    int* cls    = (int*)alloc((size_t)BS * NP * 4);
    unsigned long long* keys = (unsigned long long*)alloc((size_t)BS * CAP * 8);
    int* T      = (int*)alloc(BS * 4);
    int* M      = (int*)alloc(BS * 4);
    float4* boxes = (float4*)alloc((size_t)BS * KN * 16);
    float4* boff  = (float4*)alloc((size_t)BS * KN * 16);
    float* cscore = (float*)alloc((size_t)BS * KN * 4);
    int* ccls   = (int*)alloc((size_t)BS * KN * 4);
    uint32_t* mask = (uint32_t*)alloc((size_t)BS * KN * 64 * 4);
    uint32_t* keep = (uint32_t*)alloc((size_t)BS * 64 * 4);
    if (ws_size < off) return;  // insufficient workspace (would fail validation visibly)

    // zero hist+cnt (contiguous at ws start) and the output
    hipMemsetAsync(d_ws, 0, (size_t)BS * BINS * 4 + 256 + 64, stream);
    hipMemsetAsync(d_out, 0, (size_t)out_size * 4, stream);

    score_kernel<<<BS * NBLK, 256, 0, stream>>>(preds, score, cls, hist);
    thresh_kernel<<<BS, 64, 0, stream>>>(hist, T);
    gather_kernel<<<(BS * NP + 255) / 256, 256, 0, stream>>>(score, T, cnt, keys);
    sort_build_kernel<<<BS, 512, 0, stream>>>(keys, cnt, preds, cls, boxes, boff, cscore, ccls, M);
    iou_kernel<<<BS * 32, 256, 0, stream>>>(boff, mask);
    scan_kernel<<<BS, 64, 0, stream>>>(mask, M, keep);
    output_kernel<<<BS, 64, 0, stream>>>(keep, boxes, cscore, ccls, out);
}

// Round 2
// 490.277 us; speedup vs baseline: 1.7684x; 1.7684x over previous
//
#include <hip/hip_runtime.h>
#include <stdint.h>

#define BS 16
#define NP 25200
#define NC 80
#define DIM 85
#define KN 2048
#define CAP 4096
#define BINS 512
#define MAXD 300
#define NBLK 394   // ceil(25200/64)
#define GBLK 25    // gather blocks per batch (1024 threads each)

// ---------------------------------------------------------------- score
// One block = 64 boxes staged through LDS (coalesced). 4 lanes per box
// compute max/argmax of cls*obj with jnp.argmax first-index tie semantics.
__global__ __launch_bounds__(256) void score_kernel(const float* __restrict__ preds,
        float* __restrict__ score, int* __restrict__ clsout, int* __restrict__ hist) {
    int b = blockIdx.x / NBLK;
    int blk = blockIdx.x % NBLK;
    int i0 = blk * 64;
    int nb = min(64, NP - i0);
    __shared__ float s[64 * DIM];
    const float* p = preds + ((size_t)b * NP + i0) * DIM;
    int tot = nb * DIM;
    for (int t = threadIdx.x; t < tot; t += 256) s[t] = p[t];
    __syncthreads();
    int box = threadIdx.x >> 2, sub = threadIdx.x & 3;
    if (box < nb) {
        const float* bp = s + box * DIM;
        float obj = bp[4];
        float best = -1.0f; int bidx = sub * 20;
        #pragma unroll
        for (int c = 0; c < 20; ++c) {
            float v = bp[5 + sub * 20 + c] * obj;
            if (v > best) { best = v; bidx = sub * 20 + c; }   // strict > keeps first index
        }
        #pragma unroll
        for (int off = 1; off < 4; off <<= 1) {
            float ob = __shfl_xor(best, off);
            int   oi = __shfl_xor(bidx, off);
            if (ob > best || (ob == best && oi < bidx)) { best = ob; bidx = oi; }
        }
        if (sub == 0) {
            bool m = (obj > 0.25f) && (best > 0.25f);
            float sc = m ? best : -1.0f;
            int gi = b * NP + i0 + box;
            score[gi] = sc;
            clsout[gi] = bidx;
            if (sc > 0.0f) {
                int bin = (int)(__float_as_uint(sc) >> 16) - 0x3E80;
                bin = max(0, min(BINS - 1, bin));
                atomicAdd(&hist[b * BINS + bin], 1);   // non-returning, scattered bins
            }
        }
    }
}

// ---------------------------------------------------------------- threshold
__global__ __launch_bounds__(64) void thresh_kernel(const int* __restrict__ hist,
        int* __restrict__ T) {
    int b = blockIdx.x;
    __shared__ int h[BINS];
    for (int t = threadIdx.x; t < BINS; t += 64) h[t] = hist[b * BINS + t];
    __syncthreads();
    if (threadIdx.x == 0) {
        int c = 0, tb = 0;
        for (int bin = BINS - 1; bin >= 0; --bin) {
            c += h[bin];
            if (c >= KN) { tb = bin; break; }
        }
        T[b] = tb;   // gather everything in bins >= tb (>= 2048 elems, or all if fewer)
    }
}

// ---------------------------------------------------------------- gather
// b is block-uniform; wave ballot -> LDS counter -> ONE global atomic per
// block (25 per cnt[b] address instead of ~2200 per-lane returning atomics).
__global__ __launch_bounds__(1024) void gather_kernel(const float* __restrict__ score,
        const int* __restrict__ T, int* __restrict__ cnt,
        unsigned long long* __restrict__ keys) {
    int b = blockIdx.x / GBLK;
    int i = (blockIdx.x % GBLK) * 1024 + threadIdx.x;
    __shared__ int lcnt;
    __shared__ int gbase;
    __shared__ int wbase_s[16];
    if (threadIdx.x == 0) lcnt = 0;
    __syncthreads();
    bool want = false;
    float sc = 0.f;
    if (i < NP) {
        sc = score[b * NP + i];
        if (sc > 0.0f) {
            int bin = (int)(__float_as_uint(sc) >> 16) - 0x3E80;
            bin = max(0, min(BINS - 1, bin));
            want = bin >= T[b];
        }
    }
    unsigned long long mv = __ballot(want);
    int lane = threadIdx.x & 63;
    int wid = threadIdx.x >> 6;
    int nbelow = __popcll(mv & ((1ull << lane) - 1ull));
    if (lane == 0) {
        int wt = (int)__popcll(mv);
        wbase_s[wid] = wt ? atomicAdd(&lcnt, wt) : 0;   // LDS atomic, 16/block
    }
    __syncthreads();
    if (threadIdx.x == 0) gbase = lcnt ? atomicAdd(&cnt[b], lcnt) : 0;
    __syncthreads();
    if (want) {
        int pos = gbase + wbase_s[wid] + nbelow;
        if (pos < CAP) {
            unsigned int ii = (unsigned int)i;
            // desc sort => value desc, index asc (jax.lax.top_k tie rule)
            keys[(size_t)b * CAP + pos] =
                ((unsigned long long)__float_as_uint(sc) << 32) | (unsigned int)(~ii);
        }
    }
}

// ---------------------------------------------------------------- sort + build candidates
__global__ __launch_bounds__(512) void sort_build_kernel(const unsigned long long* __restrict__ keys,
        const int* __restrict__ cnt, const float* __restrict__ preds, const int* __restrict__ cls,
        float4* __restrict__ boxes, float4* __restrict__ boff,
        float* __restrict__ cscore, int* __restrict__ ccls, int* __restrict__ M) {
    int b = blockIdx.x;
    __shared__ unsigned long long k[CAP];
    int n = min(cnt[b], CAP);
    for (int t = threadIdx.x; t < CAP; t += 512)
        k[t] = (t < n) ? keys[(size_t)b * CAP + t] : 0ull;   // 0 pads sort last
    __syncthreads();
    for (int size = 2; size <= CAP; size <<= 1) {
        for (int stride = size >> 1; stride > 0; stride >>= 1) {
            for (int t = threadIdx.x; t < CAP / 2; t += 512) {
                int i = 2 * t - (t & (stride - 1));
                int j = i + stride;
                bool asc = (t & (size >> 1)) != 0;
                unsigned long long a = k[i], bb = k[j];
                bool sw = asc ? (a > bb) : (a < bb);
                if (sw) { k[i] = bb; k[j] = a; }
            }
            __syncthreads();
        }
    }
    int Mb = min(n, KN);
    for (int r = threadIdx.x; r < KN; r += 512) {
        float4 bx = make_float4(0.f, 0.f, 0.f, 0.f);
        float4 bo = make_float4(0.f, 0.f, 0.f, 0.f);
        float sc = 0.0f; int c = 0;
        if (r < Mb) {
            unsigned long long key = k[r];
            unsigned int i = ~(unsigned int)key;
            sc = __uint_as_float((unsigned int)(key >> 32));
            const float* p = preds + ((size_t)b * NP + i) * DIM;
            float x = p[0], y = p[1], w = p[2], h = p[3];
            float x1 = x - w * 0.5f, y1 = y - h * 0.5f;
            float x2 = x + w * 0.5f, y2 = y + h * 0.5f;
            c = cls[(size_t)b * NP + i];
            float off = (float)c * 7680.0f;
            bx = make_float4(x1, y1, x2, y2);
            bo = make_float4(x1 + off, y1 + off, x2 + off, y2 + off);
        }
        boxes [b * KN + r] = bx;
        boff  [b * KN + r] = bo;
        cscore[b * KN + r] = sc;
        ccls  [b * KN + r] = c;
    }
    if (threadIdx.x == 0) M[b] = Mb;
}

// ---------------------------------------------------------------- suppression bitmask
// mask[b][i][w] : u32 word w covers cols j in [32w, 32w+32). bit = (iou>0.45 && j>i)
__global__ __launch_bounds__(256) void iou_kernel(const float4* __restrict__ boff,
        uint32_t* __restrict__ mask) {
    int b = blockIdx.x >> 5;
    int g = blockIdx.x & 31;           // 64-row group
    __shared__ float4 sb[KN];          // 32 KB
    __shared__ uint32_t mbuf[64 * 64]; // 16 KB
    const float4* Bb = boff + b * KN;
    for (int t = threadIdx.x; t < KN; t += 256) sb[t] = Bb[t];
    __syncthreads();
    int r = threadIdx.x >> 2;
    int w0 = threadIdx.x & 3;
    int i = g * 64 + r;
    float4 bi = sb[i];
    float ai = (bi.z - bi.x) * (bi.w - bi.y);
    #pragma unroll 1
    for (int kk = 0; kk < 16; ++kk) {
        int w = w0 + kk * 4;
        uint32_t bits = 0;
        if (32 * w + 31 > i) {
            #pragma unroll
            for (int jj = 0; jj < 32; ++jj) {
                int j = 32 * w + jj;
                if (j > i) {
                    float4 bj = sb[j];
                    float aj = (bj.z - bj.x) * (bj.w - bj.y);
                    float lx = fmaxf(bi.x, bj.x), ly = fmaxf(bi.y, bj.y);
                    float rx = fminf(bi.z, bj.z), ry = fminf(bi.w, bj.w);
                    float iw = fmaxf(rx - lx, 0.0f), ih = fmaxf(ry - ly, 0.0f);
                    float inter = iw * ih;
                    float iou = inter / (ai + aj - inter + 1e-7f);  // exact IEEE div, matches ref
                    if (iou > 0.45f) bits |= (1u << jj);
                }
            }
        }
        mbuf[r * 64 + w] = bits;
    }
    __syncthreads();
    size_t base = ((size_t)b * KN + (size_t)g * 64) * 64;
    for (int t = threadIdx.x; t < 4096; t += 256) mask[base + t] = mbuf[t];
}

// ---------------------------------------------------------------- sequential greedy scan
// One wave per batch. suppressed: 32 bits/lane (lane l owns cols [32l,32l+32)).
// 64-row chunks: chunk-local suppressed bits replicated in a u64 so the serial
// dependency is pure VALU; row masks double-buffered in registers.
__global__ __launch_bounds__(64) void scan_kernel(const uint32_t* __restrict__ mask,
        const int* __restrict__ M, uint32_t* __restrict__ keepw) {
    int b = blockIdx.x;
    int lane = threadIdx.x;
    const uint32_t* mb = mask + (size_t)b * KN * 64;
    int Mb = M[b];
    uint32_t sup = 0, keep = 0;
    uint32_t cur[64], nxt[64];
    #pragma unroll
    for (int r = 0; r < 64; ++r) cur[r] = mb[r * 64 + lane];
    for (int c = 0; c < 32; ++c) {
        if (c < 31) {
            #pragma unroll
            for (int r = 0; r < 64; ++r) nxt[r] = mb[(c + 1) * 4096 + r * 64 + lane];
        }
        unsigned long long cur64 =
            ((unsigned long long)(unsigned int)__shfl((int)sup, 2 * c + 1) << 32) |
            (unsigned int)__shfl((int)sup, 2 * c);
        #pragma unroll
        for (int r = 0; r < 64; ++r) {
            int i = c * 64 + r;
            uint32_t rw = cur[r];
            unsigned long long rb64 =
                ((unsigned long long)(unsigned int)__shfl((int)rw, 2 * c + 1) << 32) |
                (unsigned int)__shfl((int)rw, 2 * c);
            bool kp = (i < Mb) && !((cur64 >> r) & 1ull);
            unsigned long long km = kp ? ~0ull : 0ull;
            cur64 |= rb64 & km;
            sup |= rw & (uint32_t)km;
            if (lane == (i >> 5)) keep |= ((uint32_t)kp) << (i & 31);
        }
        if (c < 31) {
            #pragma unroll
            for (int r = 0; r < 64; ++r) cur[r] = nxt[r];
        }
    }
    keepw[b * 64 + lane] = keep;
}

// ---------------------------------------------------------------- output
__global__ __launch_bounds__(64) void output_kernel(const uint32_t* __restrict__ keepw,
        const float4* __restrict__ boxes, const float* __restrict__ cscore,
        const int* __restrict__ ccls, float* __restrict__ out) {
    int b = blockIdx.x;
    int lane = threadIdx.x;
    uint32_t kw = keepw[b * 64 + lane];
    int cnt = __popc(kw);
    int pre = cnt;
    for (int off = 1; off < 64; off <<= 1) {
        int v = __shfl_up(pre, off);
        if (lane >= off) pre += v;
    }
    pre -= cnt;   // exclusive prefix of kept rows before this lane's 32 rows
    uint32_t m = kw;
    while (m) {
        int bit = __ffs(m) - 1;
        m &= m - 1;
        int r = lane * 32 + bit;
        int p = pre++;
        if (p < MAXD) {
            float4 bx = boxes[b * KN + r];
            float* o = out + ((size_t)b * MAXD + p) * 6;
            o[0] = bx.x * 3.0f;      // 1920/640
            o[1] = bx.y * 1.6875f;   // 1080/640
            o[2] = bx.z * 3.0f;
            o[3] = bx.w * 1.6875f;
            o[4] = cscore[b * KN + r];
            o[5] = (float)ccls[b * KN + r];
        }
    }
}

// ---------------------------------------------------------------- launch
extern "C" void kernel_launch(void* const* d_in, const int* in_sizes, int n_in,
                              void* d_out, int out_size, void* d_ws, size_t ws_size,
                              hipStream_t stream) {
    const float* preds = (const float*)d_in[0];
    float* out = (float*)d_out;
    char* ws = (char*)d_ws;
    size_t off = 0;
    auto alloc = [&](size_t bytes) -> void* {
        void* p = ws + off;
        off += (bytes + 255) & ~(size_t)255;
        return p;
    };
    int* hist   = (int*)alloc((size_t)BS * BINS * 4);
    int* cnt    = (int*)alloc(BS * 4);
    float* score = (float*)alloc((size_t)BS * NP * 4);
    int* cls    = (int*)alloc((size_t)BS * NP * 4);
    unsigned long long* keys = (unsigned long long*)alloc((size_t)BS * CAP * 8);
    int* T      = (int*)alloc(BS * 4);
    int* M      = (int*)alloc(BS * 4);
    float4* boxes = (float4*)alloc((size_t)BS * KN * 16);
    float4* boff  = (float4*)alloc((size_t)BS * KN * 16);
    float* cscore = (float*)alloc((size_t)BS * KN * 4);
    int* ccls   = (int*)alloc((size_t)BS * KN * 4);
    uint32_t* mask = (uint32_t*)alloc((size_t)BS * KN * 64 * 4);
    uint32_t* keep = (uint32_t*)alloc((size_t)BS * 64 * 4);
    if (ws_size < off) return;  // insufficient workspace (would fail validation visibly)

    // zero hist+cnt (contiguous at ws start) and the output
    hipMemsetAsync(d_ws, 0, (size_t)BS * BINS * 4 + 256 + 64, stream);
    hipMemsetAsync(d_out, 0, (size_t)out_size * 4, stream);

    score_kernel<<<BS * NBLK, 256, 0, stream>>>(preds, score, cls, hist);
    thresh_kernel<<<BS, 64, 0, stream>>>(hist, T);
    gather_kernel<<<BS * GBLK, 1024, 0, stream>>>(score, T, cnt, keys);
    sort_build_kernel<<<BS, 512, 0, stream>>>(keys, cnt, preds, cls, boxes, boff, cscore, ccls, M);
    iou_kernel<<<BS * 32, 256, 0, stream>>>(boff, mask);
    scan_kernel<<<BS, 64, 0, stream>>>(mask, M, keep);
    output_kernel<<<BS, 64, 0, stream>>>(keep, boxes, cscore, ccls, out);
}

// Round 3
// 462.429 us; speedup vs baseline: 1.8749x; 1.0602x over previous
//
#include <hip/hip_runtime.h>
#include <stdint.h>

#define BS 16
#define NP 25200
#define NC 80
#define DIM 85
#define KN 2048
#define CAP 4096
#define BINS 512
#define MAXD 300
#define NBLK 394   // ceil(25200/64)
#define GBLK 25    // gather blocks per batch (1024 threads each)

// ---------------------------------------------------------------- score
__global__ __launch_bounds__(256) void score_kernel(const float* __restrict__ preds,
        float* __restrict__ score, int* __restrict__ clsout, int* __restrict__ hist) {
    int b = blockIdx.x / NBLK;
    int blk = blockIdx.x % NBLK;
    int i0 = blk * 64;
    int nb = min(64, NP - i0);
    __shared__ float s[64 * DIM];
    const float* p = preds + ((size_t)b * NP + i0) * DIM;
    int tot = nb * DIM;
    for (int t = threadIdx.x; t < tot; t += 256) s[t] = p[t];
    __syncthreads();
    int box = threadIdx.x >> 2, sub = threadIdx.x & 3;
    if (box < nb) {
        const float* bp = s + box * DIM;
        float obj = bp[4];
        float best = -1.0f; int bidx = sub * 20;
        #pragma unroll
        for (int c = 0; c < 20; ++c) {
            float v = bp[5 + sub * 20 + c] * obj;
            if (v > best) { best = v; bidx = sub * 20 + c; }   // strict > keeps first index
        }
        #pragma unroll
        for (int off = 1; off < 4; off <<= 1) {
            float ob = __shfl_xor(best, off);
            int   oi = __shfl_xor(bidx, off);
            if (ob > best || (ob == best && oi < bidx)) { best = ob; bidx = oi; }
        }
        if (sub == 0) {
            bool m = (obj > 0.25f) && (best > 0.25f);
            float sc = m ? best : -1.0f;
            int gi = b * NP + i0 + box;
            score[gi] = sc;
            clsout[gi] = bidx;
            if (sc > 0.0f) {
                int bin = (int)(__float_as_uint(sc) >> 16) - 0x3E80;
                bin = max(0, min(BINS - 1, bin));
                atomicAdd(&hist[b * BINS + bin], 1);
            }
        }
    }
}

// ---------------------------------------------------------------- threshold
__global__ __launch_bounds__(64) void thresh_kernel(const int* __restrict__ hist,
        int* __restrict__ T) {
    int b = blockIdx.x;
    __shared__ int h[BINS];
    for (int t = threadIdx.x; t < BINS; t += 64) h[t] = hist[b * BINS + t];
    __syncthreads();
    if (threadIdx.x == 0) {
        int c = 0, tb = 0;
        for (int bin = BINS - 1; bin >= 0; --bin) {
            c += h[bin];
            if (c >= KN) { tb = bin; break; }
        }
        T[b] = tb;
    }
}

// ---------------------------------------------------------------- gather
// b block-uniform; wave ballot -> LDS counter -> one global atomic per block.
__global__ __launch_bounds__(1024) void gather_kernel(const float* __restrict__ score,
        const int* __restrict__ T, int* __restrict__ cnt,
        unsigned long long* __restrict__ keys) {
    int b = blockIdx.x / GBLK;
    int i = (blockIdx.x % GBLK) * 1024 + threadIdx.x;
    __shared__ int lcnt;
    __shared__ int gbase;
    __shared__ int wbase_s[16];
    if (threadIdx.x == 0) lcnt = 0;
    __syncthreads();
    bool want = false;
    float sc = 0.f;
    if (i < NP) {
        sc = score[b * NP + i];
        if (sc > 0.0f) {
            int bin = (int)(__float_as_uint(sc) >> 16) - 0x3E80;
            bin = max(0, min(BINS - 1, bin));
            want = bin >= T[b];
        }
    }
    unsigned long long mv = __ballot(want);
    int lane = threadIdx.x & 63;
    int wid = threadIdx.x >> 6;
    int nbelow = __popcll(mv & ((1ull << lane) - 1ull));
    if (lane == 0) {
        int wt = (int)__popcll(mv);
        wbase_s[wid] = wt ? atomicAdd(&lcnt, wt) : 0;
    }
    __syncthreads();
    if (threadIdx.x == 0) gbase = lcnt ? atomicAdd(&cnt[b], lcnt) : 0;
    __syncthreads();
    if (want) {
        int pos = gbase + wbase_s[wid] + nbelow;
        if (pos < CAP) {
            unsigned int ii = (unsigned int)i;
            keys[(size_t)b * CAP + pos] =
                ((unsigned long long)__float_as_uint(sc) << 32) | (unsigned int)(~ii);
        }
    }
}

// ---------------------------------------------------------------- sort + build candidates
__global__ __launch_bounds__(512) void sort_build_kernel(const unsigned long long* __restrict__ keys,
        const int* __restrict__ cnt, const float* __restrict__ preds, const int* __restrict__ cls,
        float4* __restrict__ boxes, float4* __restrict__ boff,
        float* __restrict__ cscore, int* __restrict__ ccls, int* __restrict__ M) {
    int b = blockIdx.x;
    __shared__ unsigned long long k[CAP];
    int n = min(cnt[b], CAP);
    for (int t = threadIdx.x; t < CAP; t += 512)
        k[t] = (t < n) ? keys[(size_t)b * CAP + t] : 0ull;
    __syncthreads();
    for (int size = 2; size <= CAP; size <<= 1) {
        for (int stride = size >> 1; stride > 0; stride >>= 1) {
            for (int t = threadIdx.x; t < CAP / 2; t += 512) {
                int i = 2 * t - (t & (stride - 1));
                int j = i + stride;
                bool asc = (t & (size >> 1)) != 0;
                unsigned long long a = k[i], bb = k[j];
                bool sw = asc ? (a > bb) : (a < bb);
                if (sw) { k[i] = bb; k[j] = a; }
            }
            __syncthreads();
        }
    }
    int Mb = min(n, KN);
    for (int r = threadIdx.x; r < KN; r += 512) {
        float4 bx = make_float4(0.f, 0.f, 0.f, 0.f);
        float4 bo = make_float4(0.f, 0.f, 0.f, 0.f);
        float sc = 0.0f; int c = 0;
        if (r < Mb) {
            unsigned long long key = k[r];
            unsigned int i = ~(unsigned int)key;
            sc = __uint_as_float((unsigned int)(key >> 32));
            const float* p = preds + ((size_t)b * NP + i) * DIM;
            float x = p[0], y = p[1], w = p[2], h = p[3];
            float x1 = x - w * 0.5f, y1 = y - h * 0.5f;
            float x2 = x + w * 0.5f, y2 = y + h * 0.5f;
            c = cls[(size_t)b * NP + i];
            float off = (float)c * 7680.0f;
            bx = make_float4(x1, y1, x2, y2);
            bo = make_float4(x1 + off, y1 + off, x2 + off, y2 + off);
        }
        boxes [b * KN + r] = bx;
        boff  [b * KN + r] = bo;
        cscore[b * KN + r] = sc;
        ccls  [b * KN + r] = c;
    }
    if (threadIdx.x == 0) M[b] = Mb;
}

// ---------------------------------------------------------------- suppression bitmask
// mask[b][i][w]: u32 word w covers cols [32w,32w+32). bit = (iou>0.45 && j>i).
// Also emits diag[b][g][128]: the 2 chunk-diagonal words of each of the 64 rows,
// laid out so scan's lane t loads element t (coalesced).
__global__ __launch_bounds__(256) void iou_kernel(const float4* __restrict__ boff,
        uint32_t* __restrict__ mask, uint32_t* __restrict__ diag) {
    int b = blockIdx.x >> 5;
    int g = blockIdx.x & 31;           // 64-row group == scan chunk
    __shared__ float4 sb[KN];          // 32 KB
    __shared__ uint32_t mbuf[64 * 64]; // 16 KB
    const float4* Bb = boff + b * KN;
    for (int t = threadIdx.x; t < KN; t += 256) sb[t] = Bb[t];
    __syncthreads();
    int r = threadIdx.x >> 2;
    int w0 = threadIdx.x & 3;
    int i = g * 64 + r;
    float4 bi = sb[i];
    float ai = (bi.z - bi.x) * (bi.w - bi.y);
    #pragma unroll 1
    for (int kk = 0; kk < 16; ++kk) {
        int w = w0 + kk * 4;
        uint32_t bits = 0;
        if (32 * w + 31 > i) {
            #pragma unroll
            for (int jj = 0; jj < 32; ++jj) {
                int j = 32 * w + jj;
                if (j > i) {
                    float4 bj = sb[j];
                    float aj = (bj.z - bj.x) * (bj.w - bj.y);
                    float lx = fmaxf(bi.x, bj.x), ly = fmaxf(bi.y, bj.y);
                    float rx = fminf(bi.z, bj.z), ry = fminf(bi.w, bj.w);
                    float iw = fmaxf(rx - lx, 0.0f), ih = fmaxf(ry - ly, 0.0f);
                    float inter = iw * ih;
                    float iou = inter / (ai + aj - inter + 1e-7f);  // IEEE div, matches np
                    if (iou > 0.45f) bits |= (1u << jj);
                }
            }
        }
        mbuf[r * 64 + w] = bits;
    }
    __syncthreads();
    size_t base = ((size_t)b * KN + (size_t)g * 64) * 64;
    for (int t = threadIdx.x; t < 4096; t += 256) mask[base + t] = mbuf[t];
    if (threadIdx.x < 128) {
        int t = threadIdx.x;
        // element t of the chunk's diag block: row t>>1, word 2g+(t&1)
        diag[((size_t)b * 32 + g) * 128 + t] = mbuf[(t >> 1) * 64 + 2 * g + (t & 1)];
    }
}

// ---------------------------------------------------------------- sequential greedy scan
// One wave per batch. sup: 32 bits/lane. Chunk state cur64 is WAVE-UNIFORM
// (built from readlane) so the per-row recurrence is a scalar bit-test +
// uniform branch; only kept rows (~300) pay for readlane/or updates.
__global__ __launch_bounds__(64) void scan_kernel(const uint32_t* __restrict__ mask,
        const uint32_t* __restrict__ diag, const int* __restrict__ M,
        uint32_t* __restrict__ keepw) {
    int b = blockIdx.x;
    int lane = threadIdx.x;
    const uint32_t* mb = mask + (size_t)b * KN * 64;
    const uint32_t* db = diag + (size_t)b * 32 * 128;
    int Mb = M[b];
    uint32_t sup = 0, keep = 0;
    uint32_t cur[64], nxt[64];
    #pragma unroll
    for (int r = 0; r < 64; ++r) cur[r] = mb[r * 64 + lane];
    for (int c = 0; c < 32; ++c) {
        if (c < 31) {
            #pragma unroll
            for (int r = 0; r < 64; ++r) nxt[r] = mb[(c + 1) * 4096 + r * 64 + lane];
        }
        // per-lane diag words for this chunk (lane t holds element t / t+64)
        uint32_t dvA = db[c * 128 + lane];
        uint32_t dvB = db[c * 128 + 64 + lane];
        int base = c * 64;
        uint64_t inval;
        if (Mb <= base) inval = ~0ull;
        else if (Mb >= base + 64) inval = 0ull;
        else inval = ~((1ull << (Mb - base)) - 1ull);
        uint64_t cur64 = inval |
            ((uint64_t)(uint32_t)__builtin_amdgcn_readlane((int)sup, 2 * c + 1) << 32) |
             (uint64_t)(uint32_t)__builtin_amdgcn_readlane((int)sup, 2 * c);
        uint64_t skeep = 0;
        #pragma unroll
        for (int r = 0; r < 64; ++r) {
            if (!((cur64 >> r) & 1ull)) {          // kept row (wave-uniform test)
                uint32_t lo, hi;
                if (r < 32) {
                    lo = (uint32_t)__builtin_amdgcn_readlane((int)dvA, 2 * r);
                    hi = (uint32_t)__builtin_amdgcn_readlane((int)dvA, 2 * r + 1);
                } else {
                    lo = (uint32_t)__builtin_amdgcn_readlane((int)dvB, 2 * (r - 32));
                    hi = (uint32_t)__builtin_amdgcn_readlane((int)dvB, 2 * (r - 32) + 1);
                }
                cur64 |= ((uint64_t)hi << 32) | lo;
                sup |= cur[r];
                skeep |= 1ull << r;
            }
        }
        if (lane == 2 * c)     keep |= (uint32_t)skeep;
        if (lane == 2 * c + 1) keep |= (uint32_t)(skeep >> 32);
        if (c < 31) {
            #pragma unroll
            for (int r = 0; r < 64; ++r) cur[r] = nxt[r];
        }
    }
    keepw[b * 64 + lane] = keep;
}

// ---------------------------------------------------------------- output
__global__ __launch_bounds__(64) void output_kernel(const uint32_t* __restrict__ keepw,
        const float4* __restrict__ boxes, const float* __restrict__ cscore,
        const int* __restrict__ ccls, float* __restrict__ out) {
    int b = blockIdx.x;
    int lane = threadIdx.x;
    uint32_t kw = keepw[b * 64 + lane];
    int cnt = __popc(kw);
    int pre = cnt;
    for (int off = 1; off < 64; off <<= 1) {
        int v = __shfl_up(pre, off);
        if (lane >= off) pre += v;
    }
    pre -= cnt;
    uint32_t m = kw;
    while (m) {
        int bit = __ffs(m) - 1;
        m &= m - 1;
        int r = lane * 32 + bit;
        int p = pre++;
        if (p < MAXD) {
            float4 bx = boxes[b * KN + r];
            float* o = out + ((size_t)b * MAXD + p) * 6;
            o[0] = bx.x * 3.0f;      // 1920/640
            o[1] = bx.y * 1.6875f;   // 1080/640
            o[2] = bx.z * 3.0f;
            o[3] = bx.w * 1.6875f;
            o[4] = cscore[b * KN + r];
            o[5] = (float)ccls[b * KN + r];
        }
    }
}

// ---------------------------------------------------------------- launch
extern "C" void kernel_launch(void* const* d_in, const int* in_sizes, int n_in,
                              void* d_out, int out_size, void* d_ws, size_t ws_size,
                              hipStream_t stream) {
    const float* preds = (const float*)d_in[0];
    float* out = (float*)d_out;
    char* ws = (char*)d_ws;
    size_t off = 0;
    auto alloc = [&](size_t bytes) -> void* {
        void* p = ws + off;
        off += (bytes + 255) & ~(size_t)255;
        return p;
    };
    int* hist   = (int*)alloc((size_t)BS * BINS * 4);
    int* cnt    = (int*)alloc(BS * 4);
    float* score = (float*)alloc((size_t)BS * NP * 4);
    int* cls    = (int*)alloc((size_t)BS * NP * 4);
    unsigned long long* keys = (unsigned long long*)alloc((size_t)BS * CAP * 8);
    int* T      = (int*)alloc(BS * 4);
    int* M      = (int*)alloc(BS * 4);
    float4* boxes = (float4*)alloc((size_t)BS * KN * 16);
    float4* boff  = (float4*)alloc((size_t)BS * KN * 16);
    float* cscore = (float*)alloc((size_t)BS * KN * 4);
    int* ccls   = (int*)alloc((size_t)BS * KN * 4);
    uint32_t* mask = (uint32_t*)alloc((size_t)BS * KN * 64 * 4);
    uint32_t* diag = (uint32_t*)alloc((size_t)BS * 32 * 128 * 4);
    uint32_t* keep = (uint32_t*)alloc((size_t)BS * 64 * 4);
    if (ws_size < off) return;

    hipMemsetAsync(d_ws, 0, (size_t)BS * BINS * 4 + 256 + 64, stream);
    hipMemsetAsync(d_out, 0, (size_t)out_size * 4, stream);

    score_kernel<<<BS * NBLK, 256, 0, stream>>>(preds, score, cls, hist);
    thresh_kernel<<<BS, 64, 0, stream>>>(hist, T);
    gather_kernel<<<BS * GBLK, 1024, 0, stream>>>(score, T, cnt, keys);
    sort_build_kernel<<<BS, 512, 0, stream>>>(keys, cnt, preds, cls, boxes, boff, cscore, ccls, M);
    iou_kernel<<<BS * 32, 256, 0, stream>>>(boff, mask, diag);
    scan_kernel<<<BS, 64, 0, stream>>>(mask, diag, M, keep);
    output_kernel<<<BS, 64, 0, stream>>>(keep, boxes, cscore, ccls, out);
}

// Round 4
// 448.803 us; speedup vs baseline: 1.9319x; 1.0304x over previous
//
#include <hip/hip_runtime.h>
#include <stdint.h>

#define BS 16
#define NP 25200
#define NC 80
#define DIM 85
#define KN 2048
#define CAP 4096
#define BINS 512
#define MAXD 300
#define NBLK 394   // ceil(25200/64)
#define GBLK 25    // gather blocks per batch (1024 threads each)

// ---------------------------------------------------------------- score
// One block = 64 boxes staged through LDS via float4 (tile word counts are
// divisible by 4 and tile base is 16B-aligned for every block).
__global__ __launch_bounds__(256) void score_kernel(const float* __restrict__ preds,
        float* __restrict__ score, int* __restrict__ clsout, int* __restrict__ hist) {
    int b = blockIdx.x / NBLK;
    int blk = blockIdx.x % NBLK;
    int i0 = blk * 64;
    int nb = min(64, NP - i0);
    __shared__ float4 s4[64 * DIM / 4];   // 21760 B
    const float4* p4 = (const float4*)(preds + ((size_t)b * NP + i0) * DIM);
    int tot4 = (nb * DIM) >> 2;           // 1360 or 1020, exact
    for (int t = threadIdx.x; t < tot4; t += 256) s4[t] = p4[t];
    __syncthreads();
    const float* s = (const float*)s4;
    int box = threadIdx.x >> 2, sub = threadIdx.x & 3;
    if (box < nb) {
        const float* bp = s + box * DIM;
        float obj = bp[4];
        float best = -1.0f; int bidx = sub * 20;
        #pragma unroll
        for (int c = 0; c < 20; ++c) {
            float v = bp[5 + sub * 20 + c] * obj;
            if (v > best) { best = v; bidx = sub * 20 + c; }   // strict > keeps first index
        }
        #pragma unroll
        for (int off = 1; off < 4; off <<= 1) {
            float ob = __shfl_xor(best, off);
            int   oi = __shfl_xor(bidx, off);
            if (ob > best || (ob == best && oi < bidx)) { best = ob; bidx = oi; }
        }
        if (sub == 0) {
            bool m = (obj > 0.25f) && (best > 0.25f);
            float sc = m ? best : -1.0f;
            int gi = b * NP + i0 + box;
            score[gi] = sc;
            clsout[gi] = bidx;
            if (sc > 0.0f) {
                int bin = (int)(__float_as_uint(sc) >> 16) - 0x3E80;
                bin = max(0, min(BINS - 1, bin));
                atomicAdd(&hist[b * BINS + bin], 1);
            }
        }
    }
}

// ---------------------------------------------------------------- gather (+fused threshold)
// Each block redundantly computes T[b] from the histogram with a wave-parallel
// suffix scan (deterministic), then ballot-aggregated compaction: one global
// atomic per block.
__global__ __launch_bounds__(1024) void gather_kernel(const float* __restrict__ score,
        const int* __restrict__ hist, int* __restrict__ cnt,
        unsigned long long* __restrict__ keys) {
    int b = blockIdx.x / GBLK;
    int i = (blockIdx.x % GBLK) * 1024 + threadIdx.x;
    __shared__ int h[BINS];
    __shared__ int sT;
    __shared__ int lcnt;
    __shared__ int gbase;
    __shared__ int wbase_s[16];
    if (threadIdx.x < BINS) h[threadIdx.x] = hist[b * BINS + threadIdx.x];
    if (threadIdx.x == 0) lcnt = 0;
    __syncthreads();
    if (threadIdx.x < 64) {
        int lane = threadIdx.x;
        int base = lane * 8;
        int v[8]; int ssum = 0;
        #pragma unroll
        for (int k = 0; k < 8; ++k) { v[k] = h[base + k]; ssum += v[k]; }
        // inclusive suffix sum over lanes (sum of s for lanes >= lane)
        int x = ssum;
        #pragma unroll
        for (int off = 1; off < 64; off <<= 1) {
            int y = __shfl_down(x, off);
            if (lane + off < 64) x += y;
        }
        int run = x - ssum;           // suffix strictly above this lane's bins
        int cand = -1;
        #pragma unroll
        for (int k = 7; k >= 0; --k) {
            run += v[k];              // run = suffix(base+k)
            if (run >= KN && cand < 0) cand = base + k;
        }
        #pragma unroll
        for (int off = 1; off < 64; off <<= 1) cand = max(cand, __shfl_xor(cand, off));
        if (lane == 0) sT = max(cand, 0);
    }
    __syncthreads();
    int T = sT;
    bool want = false;
    float sc = 0.f;
    if (i < NP) {
        sc = score[b * NP + i];
        if (sc > 0.0f) {
            int bin = (int)(__float_as_uint(sc) >> 16) - 0x3E80;
            bin = max(0, min(BINS - 1, bin));
            want = bin >= T;
        }
    }
    unsigned long long mv = __ballot(want);
    int lane = threadIdx.x & 63;
    int wid = threadIdx.x >> 6;
    int nbelow = __popcll(mv & ((1ull << lane) - 1ull));
    if (lane == 0) {
        int wt = (int)__popcll(mv);
        wbase_s[wid] = wt ? atomicAdd(&lcnt, wt) : 0;
    }
    __syncthreads();
    if (threadIdx.x == 0) gbase = lcnt ? atomicAdd(&cnt[b], lcnt) : 0;
    __syncthreads();
    if (want) {
        int pos = gbase + wbase_s[wid] + nbelow;
        if (pos < CAP) {
            unsigned int ii = (unsigned int)i;
            keys[(size_t)b * CAP + pos] =
                ((unsigned long long)__float_as_uint(sc) << 32) | (unsigned int)(~ii);
        }
    }
}

// ---------------------------------------------------------------- sort + build candidates
__global__ __launch_bounds__(512) void sort_build_kernel(const unsigned long long* __restrict__ keys,
        const int* __restrict__ cnt, const float* __restrict__ preds, const int* __restrict__ cls,
        float4* __restrict__ boxes, float4* __restrict__ boff,
        float* __restrict__ cscore, int* __restrict__ ccls, int* __restrict__ M) {
    int b = blockIdx.x;
    __shared__ unsigned long long k[CAP];
    int n = min(cnt[b], CAP);
    for (int t = threadIdx.x; t < CAP; t += 512)
        k[t] = (t < n) ? keys[(size_t)b * CAP + t] : 0ull;
    __syncthreads();
    for (int size = 2; size <= CAP; size <<= 1) {
        for (int stride = size >> 1; stride > 0; stride >>= 1) {
            for (int t = threadIdx.x; t < CAP / 2; t += 512) {
                int i = 2 * t - (t & (stride - 1));
                int j = i + stride;
                bool asc = (t & (size >> 1)) != 0;
                unsigned long long a = k[i], bb = k[j];
                bool sw = asc ? (a > bb) : (a < bb);
                if (sw) { k[i] = bb; k[j] = a; }
            }
            __syncthreads();
        }
    }
    int Mb = min(n, KN);
    for (int r = threadIdx.x; r < KN; r += 512) {
        float4 bx = make_float4(0.f, 0.f, 0.f, 0.f);
        float4 bo = make_float4(0.f, 0.f, 0.f, 0.f);
        float sc = 0.0f; int c = 0;
        if (r < Mb) {
            unsigned long long key = k[r];
            unsigned int i = ~(unsigned int)key;
            sc = __uint_as_float((unsigned int)(key >> 32));
            const float* p = preds + ((size_t)b * NP + i) * DIM;
            float x = p[0], y = p[1], w = p[2], h = p[3];
            float x1 = x - w * 0.5f, y1 = y - h * 0.5f;
            float x2 = x + w * 0.5f, y2 = y + h * 0.5f;
            c = cls[(size_t)b * NP + i];
            float off = (float)c * 7680.0f;
            bx = make_float4(x1, y1, x2, y2);
            bo = make_float4(x1 + off, y1 + off, x2 + off, y2 + off);
        }
        boxes [b * KN + r] = bx;
        boff  [b * KN + r] = bo;
        cscore[b * KN + r] = sc;
        ccls  [b * KN + r] = c;
    }
    if (threadIdx.x == 0) M[b] = Mb;
}

// ---------------------------------------------------------------- suppression bitmask
// mask[b][i][w]: u32 word w covers cols [32w,32w+32). bit = (iou>0.45 && j>i).
// diag[b][g][128]: the 2 chunk-diagonal words of each of the chunk's 64 rows.
__global__ __launch_bounds__(256) void iou_kernel(const float4* __restrict__ boff,
        uint32_t* __restrict__ mask, uint32_t* __restrict__ diag) {
    int b = blockIdx.x >> 5;
    int g = blockIdx.x & 31;           // 64-row group == scan chunk
    __shared__ float4 sb[KN];          // 32 KB
    __shared__ uint32_t mbuf[64 * 64]; // 16 KB
    const float4* Bb = boff + b * KN;
    for (int t = threadIdx.x; t < KN; t += 256) sb[t] = Bb[t];
    __syncthreads();
    int r = threadIdx.x >> 2;
    int w0 = threadIdx.x & 3;
    int i = g * 64 + r;
    float4 bi = sb[i];
    float ai = (bi.z - bi.x) * (bi.w - bi.y);
    #pragma unroll 1
    for (int kk = 0; kk < 16; ++kk) {
        int w = w0 + kk * 4;
        uint32_t bits = 0;
        if (32 * w + 31 > i) {
            #pragma unroll
            for (int jj = 0; jj < 32; ++jj) {
                int j = 32 * w + jj;
                if (j > i) {
                    float4 bj = sb[j];
                    float aj = (bj.z - bj.x) * (bj.w - bj.y);
                    float lx = fmaxf(bi.x, bj.x), ly = fmaxf(bi.y, bj.y);
                    float rx = fminf(bi.z, bj.z), ry = fminf(bi.w, bj.w);
                    float iw = fmaxf(rx - lx, 0.0f), ih = fmaxf(ry - ly, 0.0f);
                    float inter = iw * ih;
                    float iou = inter / (ai + aj - inter + 1e-7f);  // IEEE div, matches np
                    if (iou > 0.45f) bits |= (1u << jj);
                }
            }
        }
        mbuf[r * 64 + w] = bits;
    }
    __syncthreads();
    size_t base = ((size_t)b * KN + (size_t)g * 64) * 64;
    for (int t = threadIdx.x; t < 4096; t += 256) mask[base + t] = mbuf[t];
    if (threadIdx.x < 128) {
        int t = threadIdx.x;
        diag[((size_t)b * 32 + g) * 128 + t] = mbuf[(t >> 1) * 64 + 2 * g + (t & 1)];
    }
}

// ---------------------------------------------------------------- scan (+fused output)
// One wave per batch. Chunk-local state cur64 is wave-uniform (readlane), so
// per-row cost is a scalar bit-test; only kept rows update. ALL memory for
// chunk c+1 (64 mask rows + 2 diag words) is double-buffered in registers and
// issued before the compute phase, which touches no memory -> the single
// vmcnt wait lands at the register copy at chunk end.
__global__ __launch_bounds__(64) void scan_kernel(const uint32_t* __restrict__ mask,
        const uint32_t* __restrict__ diag, const int* __restrict__ M,
        const float4* __restrict__ boxes, const float* __restrict__ cscore,
        const int* __restrict__ ccls, float* __restrict__ out) {
    int b = blockIdx.x;
    int lane = threadIdx.x;
    const uint32_t* mb = mask + (size_t)b * KN * 64;
    const uint32_t* db = diag + (size_t)b * 32 * 128;
    int Mb = M[b];
    uint32_t sup = 0, keep = 0;
    uint32_t cur[64], nxt[64];
    uint32_t dA, dB, ndA = 0, ndB = 0;
    #pragma unroll
    for (int r = 0; r < 64; ++r) cur[r] = mb[r * 64 + lane];
    dA = db[lane];
    dB = db[64 + lane];
    for (int c = 0; c < 32; ++c) {
        if (c < 31) {
            #pragma unroll
            for (int r = 0; r < 64; ++r) nxt[r] = mb[(c + 1) * 4096 + r * 64 + lane];
            ndA = db[(c + 1) * 128 + lane];
            ndB = db[(c + 1) * 128 + 64 + lane];
        }
        int base = c * 64;
        uint64_t inval;
        if (Mb <= base) inval = ~0ull;
        else if (Mb >= base + 64) inval = 0ull;
        else inval = ~((1ull << (Mb - base)) - 1ull);
        uint64_t cur64 = inval |
            ((uint64_t)(uint32_t)__builtin_amdgcn_readlane((int)sup, 2 * c + 1) << 32) |
             (uint64_t)(uint32_t)__builtin_amdgcn_readlane((int)sup, 2 * c);
        uint64_t skeep = 0;
        #pragma unroll
        for (int r = 0; r < 64; ++r) {
            if (!((cur64 >> r) & 1ull)) {          // kept row (wave-uniform test)
                uint32_t lo, hi;
                if (r < 32) {
                    lo = (uint32_t)__builtin_amdgcn_readlane((int)dA, 2 * r);
                    hi = (uint32_t)__builtin_amdgcn_readlane((int)dA, 2 * r + 1);
                } else {
                    lo = (uint32_t)__builtin_amdgcn_readlane((int)dB, 2 * (r - 32));
                    hi = (uint32_t)__builtin_amdgcn_readlane((int)dB, 2 * (r - 32) + 1);
                }
                cur64 |= ((uint64_t)hi << 32) | lo;
                sup |= cur[r];
                skeep |= 1ull << r;
            }
        }
        if (lane == 2 * c)     keep |= (uint32_t)skeep;
        if (lane == 2 * c + 1) keep |= (uint32_t)(skeep >> 32);
        if (c < 31) {
            #pragma unroll
            for (int r = 0; r < 64; ++r) cur[r] = nxt[r];
            dA = ndA; dB = ndB;
        }
    }
    // ---- fused output: popcount prefix over keep bits -> scatter kept rows
    int cnt = __popc(keep);
    int pre = cnt;
    for (int off = 1; off < 64; off <<= 1) {
        int v = __shfl_up(pre, off);
        if (lane >= off) pre += v;
    }
    pre -= cnt;
    uint32_t m = keep;
    while (m) {
        int bit = __ffs(m) - 1;
        m &= m - 1;
        int r = lane * 32 + bit;
        int p = pre++;
        if (p < MAXD) {
            float4 bx = boxes[b * KN + r];
            float* o = out + ((size_t)b * MAXD + p) * 6;
            o[0] = bx.x * 3.0f;      // 1920/640
            o[1] = bx.y * 1.6875f;   // 1080/640
            o[2] = bx.z * 3.0f;
            o[3] = bx.w * 1.6875f;
            o[4] = cscore[b * KN + r];
            o[5] = (float)ccls[b * KN + r];
        }
    }
}

// ---------------------------------------------------------------- launch
extern "C" void kernel_launch(void* const* d_in, const int* in_sizes, int n_in,
                              void* d_out, int out_size, void* d_ws, size_t ws_size,
                              hipStream_t stream) {
    const float* preds = (const float*)d_in[0];
    float* out = (float*)d_out;
    char* ws = (char*)d_ws;
    size_t off = 0;
    auto alloc = [&](size_t bytes) -> void* {
        void* p = ws + off;
        off += (bytes + 255) & ~(size_t)255;
        return p;
    };
    int* hist   = (int*)alloc((size_t)BS * BINS * 4);   // must stay first (memset)
    int* cnt    = (int*)alloc(BS * 4);                  // must stay second (memset)
    float* score = (float*)alloc((size_t)BS * NP * 4);
    int* cls    = (int*)alloc((size_t)BS * NP * 4);
    unsigned long long* keys = (unsigned long long*)alloc((size_t)BS * CAP * 8);
    int* M      = (int*)alloc(BS * 4);
    float4* boxes = (float4*)alloc((size_t)BS * KN * 16);
    float4* boff  = (float4*)alloc((size_t)BS * KN * 16);
    float* cscore = (float*)alloc((size_t)BS * KN * 4);
    int* ccls   = (int*)alloc((size_t)BS * KN * 4);
    uint32_t* mask = (uint32_t*)alloc((size_t)BS * KN * 64 * 4);
    uint32_t* diag = (uint32_t*)alloc((size_t)BS * 32 * 128 * 4);
    if (ws_size < off) return;

    hipMemsetAsync(d_ws, 0, (size_t)BS * BINS * 4 + 256 + 64, stream);  // hist + cnt
    hipMemsetAsync(d_out, 0, (size_t)out_size * 4, stream);

    score_kernel<<<BS * NBLK, 256, 0, stream>>>(preds, score, cls, hist);
    gather_kernel<<<BS * GBLK, 1024, 0, stream>>>(score, hist, cnt, keys);
    sort_build_kernel<<<BS, 512, 0, stream>>>(keys, cnt, preds, cls, boxes, boff, cscore, ccls, M);
    iou_kernel<<<BS * 32, 256, 0, stream>>>(boff, mask, diag);
    scan_kernel<<<BS, 64, 0, stream>>>(mask, diag, M, boxes, cscore, ccls, out);
}